// Round 1
// 293.124 us; speedup vs baseline: 1.1381x; 1.1381x over previous
//
#include <hip/hip_runtime.h>

#define N_USERS 400000
#define N_ITEMS 200000
#define NNODES  600000   // N_USERS + N_ITEMS
#define D 64
#define B 8192

// ---------------------------------------------------------------------------
// bf16 helpers
// ---------------------------------------------------------------------------
__device__ __forceinline__ float bflo(unsigned u) { return __uint_as_float(u << 16); }
__device__ __forceinline__ float bfhi(unsigned u) { return __uint_as_float(u & 0xffff0000u); }
__device__ __forceinline__ unsigned f2bf(float f) {   // round-to-nearest-even
    unsigned u = __float_as_uint(f);
    unsigned r = u + 0x7fffu + ((u >> 16) & 1u);
    return r >> 16;
}

// acc[0..7] += v * bf16x8(word4)
__device__ __forceinline__ void unpack_fma(float* acc, uint4 wv, float v) {
    acc[0] += v * bflo(wv.x); acc[1] += v * bfhi(wv.x);
    acc[2] += v * bflo(wv.y); acc[3] += v * bfhi(wv.y);
    acc[4] += v * bflo(wv.z); acc[5] += v * bfhi(wv.z);
    acc[6] += v * bflo(wv.w); acc[7] += v * bfhi(wv.w);
}

// ---------------------------------------------------------------------------
// CSR build
// ---------------------------------------------------------------------------
__global__ void k_hist(const int* __restrict__ rows, int* __restrict__ deg, int nnz) {
    int tid = blockIdx.x * blockDim.x + threadIdx.x;
    if (tid >= nnz) return;
    atomicAdd(&deg[rows[tid]], 1);
}

// exclusive per-block scan of deg (in place) + block totals + dinv (fused)
__global__ void k_scan1(int* __restrict__ deg, int* __restrict__ sums,
                        float* __restrict__ dinv, int n) {
    __shared__ int lds[256];
    int i = blockIdx.x * 256 + threadIdx.x;
    int v = (i < n) ? deg[i] : 0;
    if (i < n) dinv[i] = (v > 0) ? (float)(1.0 / sqrt((double)v)) : 0.0f;
    lds[threadIdx.x] = v;
    __syncthreads();
    for (int off = 1; off < 256; off <<= 1) {
        int t = (threadIdx.x >= off) ? lds[threadIdx.x - off] : 0;
        __syncthreads();
        lds[threadIdx.x] += t;
        __syncthreads();
    }
    int inc = lds[threadIdx.x];
    if (i < n) deg[i] = inc - v;
    if (threadIdx.x == 255) sums[blockIdx.x] = inc;
}

// single-block (1024 threads) exclusive scan of sums[0..n)
__global__ void k_scan2(int* __restrict__ sums, int n) {
    __shared__ int lds[1024];
    __shared__ int carry;
    if (threadIdx.x == 0) carry = 0;
    __syncthreads();
    for (int base = 0; base < n; base += 1024) {
        int i = base + threadIdx.x;
        int v = (i < n) ? sums[i] : 0;
        lds[threadIdx.x] = v;
        __syncthreads();
        for (int off = 1; off < 1024; off <<= 1) {
            int t = (threadIdx.x >= off) ? lds[threadIdx.x - off] : 0;
            __syncthreads();
            lds[threadIdx.x] += t;
            __syncthreads();
        }
        int inc = lds[threadIdx.x];
        if (i < n) sums[i] = (inc - v) + carry;
        __syncthreads();
        if (threadIdx.x == 1023) carry += lds[1023];
        __syncthreads();
    }
}

__global__ void k_scan3(const int* __restrict__ deg, const int* __restrict__ sums,
                        int* __restrict__ row_ptr, int* __restrict__ nextp, int nnz) {
    int i = blockIdx.x * blockDim.x + threadIdx.x;
    if (i >= NNODES) return;
    int rp = deg[i] + sums[i >> 8];
    row_ptr[i] = rp;
    nextp[i] = rp;
    if (i == 0) row_ptr[NNODES] = nnz;
}

__global__ void k_scatter(const int* __restrict__ rows, const int* __restrict__ cols,
                          int* __restrict__ nextp, int* __restrict__ pcol, int nnz) {
    int e = blockIdx.x * blockDim.x + threadIdx.x;
    if (e >= nnz) return;
    int r = rows[e];
    int p = atomicAdd(&nextp[r], 1);
    pcol[p] = cols[e];
}

// ---------------------------------------------------------------------------
// sizes[r] = popcount of prefix-mask row.
// Vectorized: 16 threads per row, int4 (16 B/lane) loads, shfl-reduce sum.
// Only pass that touches the 153.6 MB masks -> must run at streaming BW.
// ---------------------------------------------------------------------------
__global__ void k_sizes(const int* __restrict__ um, const int* __restrict__ im,
                        int* __restrict__ sizes) {
    int gtid = blockIdx.x * blockDim.x + threadIdx.x;
    int r = gtid >> 4;                 // 16 threads per row
    int q = gtid & 15;                 // int4 slot within the row
    if (r >= NNODES) return;
    const int4* p = (const int4*)((r < N_USERS) ? um + (size_t)r * D
                                                : im + (size_t)(r - N_USERS) * D);
    int4 v = p[q];                     // 16 B coalesced per lane
    int s = v.x + v.y + v.z + v.w;     // mask entries are 0/1
    s += __shfl_xor(s, 1);
    s += __shfl_xor(s, 2);
    s += __shfl_xor(s, 4);
    s += __shfl_xor(s, 8);
    if (q == 0) sizes[r] = s;
}

// ---------------------------------------------------------------------------
// Frontier marking.
// k_mark_s: per sample row r: flag2[r]=flag1[r]=1; flag2[col]=1 for its cols.
// k_mark_1: per row with flag2 set: flag1[col]=1 for its cols.
// ---------------------------------------------------------------------------
__global__ void k_mark_s(const int* __restrict__ row_ptr, const int* __restrict__ pcol,
                         const int* __restrict__ users, const int* __restrict__ pos,
                         const int* __restrict__ neg,
                         char* __restrict__ flag1, char* __restrict__ flag2) {
    int slot = blockIdx.x * blockDim.x + threadIdx.x;
    if (slot >= 3 * B) return;
    int set = slot / B;
    int b = slot - set * B;
    int r;
    if (set == 0)      r = users[b];
    else if (set == 1) r = N_USERS + pos[b];
    else               r = N_USERS + neg[b];
    flag2[r] = 1;
    flag1[r] = 1;
    int e = row_ptr[r + 1];
    for (int i = row_ptr[r]; i < e; ++i) flag2[pcol[i]] = 1;
}

__global__ void k_mark_1(const int* __restrict__ row_ptr, const int* __restrict__ pcol,
                         const char* __restrict__ flag2, char* __restrict__ flag1) {
    int r = blockIdx.x * blockDim.x + threadIdx.x;
    if (r >= NNODES) return;
    if (!flag2[r]) return;
    int e = row_ptr[r + 1];
    for (int i = row_ptr[r]; i < e; ++i) flag1[pcol[i]] = 1;
}

// ---------------------------------------------------------------------------
// Layer-1 SPMM from RAW f32 embeddings with inline prefix-mask:
//   y1[r] = sum dinv[r]*dinv[c] * (emb[c] masked to sizes[c]),  flag1 rows only.
// 8 threads/row, 8 f32 cols each, bf16 output.
// ---------------------------------------------------------------------------
__global__ void k_spmm1(const int* __restrict__ row_ptr, const int* __restrict__ pcol,
                        const float* __restrict__ dinv, const int* __restrict__ sizes,
                        const char* __restrict__ flag1,
                        const float* __restrict__ ue, const float* __restrict__ ie,
                        unsigned* __restrict__ y1) {
    int tid = blockIdx.x * blockDim.x + threadIdx.x;
    int r = tid >> 3;
    if (r >= NNODES) return;
    if (!flag1[r]) return;
    int c8 = (tid & 7) << 3;          // f32 col base
    int s = row_ptr[r];
    int e = row_ptr[r + 1];
    float dr = dinv[r];
    float acc[8] = {0.f, 0.f, 0.f, 0.f, 0.f, 0.f, 0.f, 0.f};
    for (int i = s; i < e; ++i) {
        int c = pcol[i];
        float v = dr * dinv[c];
        int sz = sizes[c];
        const float* p = ((c < N_USERS) ? ue + (size_t)c * D
                                        : ie + (size_t)(c - N_USERS) * D) + c8;
        float4 e0 = *(const float4*)p;
        float4 e1 = *(const float4*)(p + 4);
        acc[0] += v * ((c8 + 0 < sz) ? e0.x : 0.f);
        acc[1] += v * ((c8 + 1 < sz) ? e0.y : 0.f);
        acc[2] += v * ((c8 + 2 < sz) ? e0.z : 0.f);
        acc[3] += v * ((c8 + 3 < sz) ? e0.w : 0.f);
        acc[4] += v * ((c8 + 4 < sz) ? e1.x : 0.f);
        acc[5] += v * ((c8 + 5 < sz) ? e1.y : 0.f);
        acc[6] += v * ((c8 + 6 < sz) ? e1.z : 0.f);
        acc[7] += v * ((c8 + 7 < sz) ? e1.w : 0.f);
    }
    uint4 o;
    o.x = f2bf(acc[0]) | (f2bf(acc[1]) << 16);
    o.y = f2bf(acc[2]) | (f2bf(acc[3]) << 16);
    o.z = f2bf(acc[4]) | (f2bf(acc[5]) << 16);
    o.w = f2bf(acc[6]) | (f2bf(acc[7]) << 16);
    *(uint4*)(y1 + (size_t)r * 32 + (tid & 7) * 4) = o;
}

// ---------------------------------------------------------------------------
// Layer-2 bf16 SPMM, flag2 rows only: x2[r] = sum val * y1[col].
// ---------------------------------------------------------------------------
__global__ void k_spmm2(const int* __restrict__ row_ptr, const int* __restrict__ pcol,
                        const float* __restrict__ dinv, const char* __restrict__ flag2,
                        const unsigned* __restrict__ y1, unsigned* __restrict__ x2) {
    int tid = blockIdx.x * blockDim.x + threadIdx.x;
    int r = tid >> 3;
    if (r >= NNODES) return;
    if (!flag2[r]) return;
    int cp = (tid & 7) << 2;
    int s = row_ptr[r];
    int e = row_ptr[r + 1];
    float dr = dinv[r];
    float acc[8] = {0.f, 0.f, 0.f, 0.f, 0.f, 0.f, 0.f, 0.f};
    int i = s;
    for (; i + 1 < e; i += 2) {
        int c0 = pcol[i], c1 = pcol[i + 1];
        float v0 = dr * dinv[c0], v1 = dr * dinv[c1];
        uint4 w0 = *(const uint4*)(y1 + (size_t)c0 * 32 + cp);
        uint4 w1 = *(const uint4*)(y1 + (size_t)c1 * 32 + cp);
        unpack_fma(acc, w0, v0);
        unpack_fma(acc, w1, v1);
    }
    if (i < e) {
        int c0 = pcol[i];
        float v0 = dr * dinv[c0];
        uint4 w0 = *(const uint4*)(y1 + (size_t)c0 * 32 + cp);
        unpack_fma(acc, w0, v0);
    }
    uint4 o;
    o.x = f2bf(acc[0]) | (f2bf(acc[1]) << 16);
    o.y = f2bf(acc[2]) | (f2bf(acc[3]) << 16);
    o.z = f2bf(acc[4]) | (f2bf(acc[5]) << 16);
    o.w = f2bf(acc[6]) | (f2bf(acc[7]) << 16);
    *(uint4*)(x2 + (size_t)r * 32 + cp) = o;
}

// ---------------------------------------------------------------------------
// Final sampled layer, everything fused:
//   x0r   = masked f32 emb row (exact)
//   out[slot]      = (x0r + y1[r] + x2[r] + sum val * x2[col]) * 0.25
//   out[3B + slot] = x0r                     (ego)
// ---------------------------------------------------------------------------
__global__ void k_spmm3(const int* __restrict__ row_ptr, const int* __restrict__ pcol,
                        const float* __restrict__ dinv, const int* __restrict__ sizes,
                        const float* __restrict__ ue, const float* __restrict__ ie,
                        const unsigned* __restrict__ y1, const unsigned* __restrict__ x2,
                        const int* __restrict__ users, const int* __restrict__ pos,
                        const int* __restrict__ neg, float* __restrict__ out) {
    int tid = blockIdx.x * blockDim.x + threadIdx.x;
    int slot = tid >> 3;
    if (slot >= 3 * B) return;
    int cp = (tid & 7) << 2;          // uint base
    int c8 = (tid & 7) << 3;          // f32 col base
    int set = slot / B;
    int b = slot - set * B;
    int r;
    if (set == 0)      r = users[b];
    else if (set == 1) r = N_USERS + pos[b];
    else               r = N_USERS + neg[b];
    int s = row_ptr[r];
    int e = row_ptr[r + 1];
    float dr = dinv[r];
    float acc[8] = {0.f, 0.f, 0.f, 0.f, 0.f, 0.f, 0.f, 0.f};
    uint4 g1 = *(const uint4*)(y1 + (size_t)r * 32 + cp);
    uint4 g2 = *(const uint4*)(x2 + (size_t)r * 32 + cp);
    unpack_fma(acc, g1, 1.0f);
    unpack_fma(acc, g2, 1.0f);
    int i = s;
    for (; i + 1 < e; i += 2) {
        int c0 = pcol[i], c1 = pcol[i + 1];
        float v0 = dr * dinv[c0], v1 = dr * dinv[c1];
        uint4 w0 = *(const uint4*)(x2 + (size_t)c0 * 32 + cp);
        uint4 w1 = *(const uint4*)(x2 + (size_t)c1 * 32 + cp);
        unpack_fma(acc, w0, v0);
        unpack_fma(acc, w1, v1);
    }
    if (i < e) {
        int c0 = pcol[i];
        float v0 = dr * dinv[c0];
        uint4 w0 = *(const uint4*)(x2 + (size_t)c0 * 32 + cp);
        unpack_fma(acc, w0, v0);
    }
    // exact masked f32 ego row
    const float* p = ((r < N_USERS) ? ue + (size_t)r * D
                                    : ie + (size_t)(r - N_USERS) * D) + c8;
    float4 e0 = *(const float4*)p;
    float4 e1 = *(const float4*)(p + 4);
    int sz = sizes[r];
    e0.x = (c8 + 0 < sz) ? e0.x : 0.f; e0.y = (c8 + 1 < sz) ? e0.y : 0.f;
    e0.z = (c8 + 2 < sz) ? e0.z : 0.f; e0.w = (c8 + 3 < sz) ? e0.w : 0.f;
    e1.x = (c8 + 4 < sz) ? e1.x : 0.f; e1.y = (c8 + 5 < sz) ? e1.y : 0.f;
    e1.z = (c8 + 6 < sz) ? e1.z : 0.f; e1.w = (c8 + 7 < sz) ? e1.w : 0.f;
    float4 oa, ob;
    oa.x = (e0.x + acc[0]) * 0.25f; oa.y = (e0.y + acc[1]) * 0.25f;
    oa.z = (e0.z + acc[2]) * 0.25f; oa.w = (e0.w + acc[3]) * 0.25f;
    ob.x = (e1.x + acc[4]) * 0.25f; ob.y = (e1.y + acc[5]) * 0.25f;
    ob.z = (e1.z + acc[6]) * 0.25f; ob.w = (e1.w + acc[7]) * 0.25f;
    float* o0 = out + (size_t)slot * D + c8;
    float* o1 = out + (size_t)(3 * B + slot) * D + c8;
    *(float4*)o0 = oa; *(float4*)(o0 + 4) = ob;
    *(float4*)o1 = e0; *(float4*)(o1 + 4) = e1;
}

extern "C" void kernel_launch(void* const* d_in, const int* in_sizes, int n_in,
                              void* d_out, int out_size, void* d_ws, size_t ws_size,
                              hipStream_t stream) {
    const float* ue   = (const float*)d_in[0];
    const float* ie   = (const float*)d_in[1];
    const int*   um   = (const int*)d_in[2];
    const int*   im   = (const int*)d_in[3];
    const int*   rows = (const int*)d_in[4];
    const int*   cols = (const int*)d_in[5];
    const int*   users = (const int*)d_in[7];
    const int*   pos   = (const int*)d_in[8];
    const int*   neg   = (const int*)d_in[9];
    int nnz = in_sizes[4];

    float* out = (float*)d_out;

    // workspace layout (16B-aligned bf16 node buffers first)
    unsigned short* Y1 = (unsigned short*)d_ws;         // NNODES*D bf16
    unsigned short* X2 = Y1 + (size_t)NNODES * D;       // NNODES*D bf16
    int*   deg     = (int*)(X2 + (size_t)NNODES * D);   // NNODES
    int*   row_ptr = deg + NNODES;                      // NNODES+1
    int*   nextp   = row_ptr + NNODES + 1;              // NNODES
    int*   sizes   = nextp + NNODES;                    // NNODES
    int*   sums    = sizes + NNODES;                    // up to 4096
    float* dinv    = (float*)(sums + 4096);             // NNODES
    int*   pcol    = (int*)(dinv + NNODES);             // nnz
    char*  flag1   = (char*)(pcol + nnz);               // NNODES
    char*  flag2   = flag1 + NNODES;                    // NNODES

    const int blk = 256;
    const int scan_blocks = (NNODES + 255) / 256;       // 2344

    // --- CSR build + flag clear ---
    hipMemsetAsync(deg, 0, (size_t)NNODES * sizeof(int), stream);
    hipMemsetAsync(flag1, 0, (size_t)2 * NNODES, stream);
    k_hist<<<(nnz + blk - 1) / blk, blk, 0, stream>>>(rows, deg, nnz);
    k_scan1<<<scan_blocks, 256, 0, stream>>>(deg, sums, dinv, NNODES);
    k_scan2<<<1, 1024, 0, stream>>>(sums, scan_blocks);
    k_scan3<<<(NNODES + blk - 1) / blk, blk, 0, stream>>>(deg, sums, row_ptr, nextp, nnz);
    k_scatter<<<(nnz + blk - 1) / blk, blk, 0, stream>>>(rows, cols, nextp, pcol, nnz);

    // --- prefix-mask sizes (only pass over the masks): 16 threads/row, int4 ---
    k_sizes<<<(NNODES * 16 + blk - 1) / blk, blk, 0, stream>>>(um, im, sizes);

    // --- frontier marking ---
    k_mark_s<<<(3 * B + blk - 1) / blk, blk, 0, stream>>>(row_ptr, pcol, users, pos, neg,
                                                          flag1, flag2);
    k_mark_1<<<(NNODES + blk - 1) / blk, blk, 0, stream>>>(row_ptr, pcol, flag2, flag1);

    int n_full = NNODES * 8;
    int n_samp = 3 * B * 8;

    // layer 1 (flag1 rows): Y1 = A * masked_emb
    k_spmm1<<<(n_full + blk - 1) / blk, blk, 0, stream>>>(row_ptr, pcol, dinv, sizes, flag1,
                                                          ue, ie, (unsigned*)Y1);

    // layer 2 (flag2 rows): X2 = A * Y1
    k_spmm2<<<(n_full + blk - 1) / blk, blk, 0, stream>>>(row_ptr, pcol, dinv, flag2,
                                                          (const unsigned*)Y1, (unsigned*)X2);

    // layer 3: sampled rows, fully fused epilogue + ego
    k_spmm3<<<(n_samp + blk - 1) / blk, blk, 0, stream>>>(row_ptr, pcol, dinv, sizes,
                                                          ue, ie,
                                                          (const unsigned*)Y1,
                                                          (const unsigned*)X2,
                                                          users, pos, neg, out);
}

// Round 2
// 271.792 us; speedup vs baseline: 1.2274x; 1.0785x over previous
//
#include <hip/hip_runtime.h>

#define N_USERS 400000
#define N_ITEMS 200000
#define NNODES  600000   // N_USERS + N_ITEMS
#define D 64
#define B 8192

// ---------------------------------------------------------------------------
// bf16 helpers
// ---------------------------------------------------------------------------
__device__ __forceinline__ float bflo(unsigned u) { return __uint_as_float(u << 16); }
__device__ __forceinline__ float bfhi(unsigned u) { return __uint_as_float(u & 0xffff0000u); }
__device__ __forceinline__ unsigned f2bf(float f) {   // round-to-nearest-even
    unsigned u = __float_as_uint(f);
    unsigned r = u + 0x7fffu + ((u >> 16) & 1u);
    return r >> 16;
}

// acc[0..7] += v * bf16x8(word4)
__device__ __forceinline__ void unpack_fma(float* acc, uint4 wv, float v) {
    acc[0] += v * bflo(wv.x); acc[1] += v * bfhi(wv.x);
    acc[2] += v * bflo(wv.y); acc[3] += v * bfhi(wv.y);
    acc[4] += v * bflo(wv.z); acc[5] += v * bfhi(wv.z);
    acc[6] += v * bflo(wv.w); acc[7] += v * bfhi(wv.w);
}

// ---------------------------------------------------------------------------
// CSR build
// ---------------------------------------------------------------------------
__global__ void k_hist(const int* __restrict__ rows, int* __restrict__ deg, int nnz) {
    int tid = blockIdx.x * blockDim.x + threadIdx.x;
    if (tid >= nnz) return;
    atomicAdd(&deg[rows[tid]], 1);
}

// exclusive per-block scan of deg (in place) + block totals + dinv (fused)
__global__ void k_scan1(int* __restrict__ deg, int* __restrict__ sums,
                        float* __restrict__ dinv, int n) {
    __shared__ int lds[256];
    int i = blockIdx.x * 256 + threadIdx.x;
    int v = (i < n) ? deg[i] : 0;
    if (i < n) dinv[i] = (v > 0) ? (float)(1.0 / sqrt((double)v)) : 0.0f;
    lds[threadIdx.x] = v;
    __syncthreads();
    for (int off = 1; off < 256; off <<= 1) {
        int t = (threadIdx.x >= off) ? lds[threadIdx.x - off] : 0;
        __syncthreads();
        lds[threadIdx.x] += t;
        __syncthreads();
    }
    int inc = lds[threadIdx.x];
    if (i < n) deg[i] = inc - v;
    if (threadIdx.x == 255) sums[blockIdx.x] = inc;
}

// single-block (1024 threads) exclusive scan of sums[0..n)
__global__ void k_scan2(int* __restrict__ sums, int n) {
    __shared__ int lds[1024];
    __shared__ int carry;
    if (threadIdx.x == 0) carry = 0;
    __syncthreads();
    for (int base = 0; base < n; base += 1024) {
        int i = base + threadIdx.x;
        int v = (i < n) ? sums[i] : 0;
        lds[threadIdx.x] = v;
        __syncthreads();
        for (int off = 1; off < 1024; off <<= 1) {
            int t = (threadIdx.x >= off) ? lds[threadIdx.x - off] : 0;
            __syncthreads();
            lds[threadIdx.x] += t;
            __syncthreads();
        }
        int inc = lds[threadIdx.x];
        if (i < n) sums[i] = (inc - v) + carry;
        __syncthreads();
        if (threadIdx.x == 1023) carry += lds[1023];
        __syncthreads();
    }
}

// scan3 + sample-flag seeding fused (extra blocks at the tail)
__global__ void k_scan3_flags(const int* __restrict__ deg, const int* __restrict__ sums,
                              int* __restrict__ row_ptr, int* __restrict__ nextp,
                              const int* __restrict__ users, const int* __restrict__ pos,
                              const int* __restrict__ neg,
                              char* __restrict__ flag1, char* __restrict__ flag2,
                              int nnz, int scan_blocks) {
    int bid = blockIdx.x;
    if (bid < scan_blocks) {
        int i = bid * blockDim.x + threadIdx.x;
        if (i >= NNODES) return;
        int rp = deg[i] + sums[i >> 8];
        row_ptr[i] = rp;
        nextp[i] = rp;
        if (i == 0) row_ptr[NNODES] = nnz;
    } else {
        int slot = (bid - scan_blocks) * blockDim.x + threadIdx.x;
        if (slot >= 3 * B) return;
        int set = slot / B;
        int b = slot - set * B;
        int r;
        if (set == 0)      r = users[b];
        else if (set == 1) r = N_USERS + pos[b];
        else               r = N_USERS + neg[b];
        flag2[r] = 1;
        flag1[r] = 1;
    }
}

// ---------------------------------------------------------------------------
// FAT kernel: three independent jobs overlapped under the latency-bound
// scatter (scatter: VALUBusy 0.36%, 12% HBM -> machine idle).
//   role 0 (bid%10==0): CSR scatter        (4688 sub-blocks)
//   role 1..8:          mask popcount      (37504 sub-blocks, streams 153.6MB)
//   role 9:             COO mark pass1:    flag2[col]=1 where flag2[row]
// Interleaved roles keep streaming blocks co-resident with scatter blocks.
// Race note (pass1): flag writes are monotone 0->1; concurrent readers may
// see early 1s -> benign superset marking (extra rows computed, never read).
// ---------------------------------------------------------------------------
__global__ void k_fat(const int* __restrict__ rows, const int* __restrict__ cols,
                      int* __restrict__ nextp, int* __restrict__ pcol,
                      const int* __restrict__ um, const int* __restrict__ im,
                      int* __restrict__ sizes, char* __restrict__ flag2, int nnz) {
    int bid = blockIdx.x;
    int grp = bid / 10;
    int role = bid - grp * 10;
    if (role == 0) {
        // --- scatter ---
        int e = grp * 256 + threadIdx.x;
        if (e >= nnz) return;
        int r = rows[e];
        int p = atomicAdd(&nextp[r], 1);
        pcol[p] = cols[e];
    } else if (role == 9) {
        // --- mark pass1 (COO) ---
        int e = grp * 256 + threadIdx.x;
        if (e >= nnz) return;
        if (flag2[rows[e]]) flag2[cols[e]] = 1;
    } else {
        // --- sizes: 16 threads/row, int4 loads, shfl reduce ---
        int sbid = grp * 8 + (role - 1);
        int gtid = sbid * 256 + threadIdx.x;
        int r = gtid >> 4;
        int q = gtid & 15;
        if (r >= NNODES) return;
        const int4* p = (const int4*)((r < N_USERS) ? um + (size_t)r * D
                                                    : im + (size_t)(r - N_USERS) * D);
        int4 v = p[q];
        int s = v.x + v.y + v.z + v.w;
        s += __shfl_xor(s, 1);
        s += __shfl_xor(s, 2);
        s += __shfl_xor(s, 4);
        s += __shfl_xor(s, 8);
        if (q == 0) sizes[r] = s;
    }
}

// ---------------------------------------------------------------------------
// COO mark pass2: flag1[col]=1 for edges with flag2[row]; plus flag1 |= flag2.
// flag2 is stable (read-only) here.
// ---------------------------------------------------------------------------
__global__ void k_pass2(const int* __restrict__ rows, const int* __restrict__ cols,
                        const char* __restrict__ flag2, char* __restrict__ flag1,
                        int nnz) {
    int t = blockIdx.x * blockDim.x + threadIdx.x;
    if (t < nnz) {
        if (flag2[rows[t]]) flag1[cols[t]] = 1;
    } else {
        int r = t - nnz;
        if (r < NNODES) {
            if (flag2[r]) flag1[r] = 1;
        }
    }
}

// ---------------------------------------------------------------------------
// Layer-1 SPMM from RAW f32 embeddings with inline prefix-mask:
//   y1[r] = sum dinv[r]*dinv[c] * (emb[c] masked to sizes[c]),  flag1 rows only.
// 8 threads/row, 8 f32 cols each, bf16 output.
// ---------------------------------------------------------------------------
__global__ void k_spmm1(const int* __restrict__ row_ptr, const int* __restrict__ pcol,
                        const float* __restrict__ dinv, const int* __restrict__ sizes,
                        const char* __restrict__ flag1,
                        const float* __restrict__ ue, const float* __restrict__ ie,
                        unsigned* __restrict__ y1) {
    int tid = blockIdx.x * blockDim.x + threadIdx.x;
    int r = tid >> 3;
    if (r >= NNODES) return;
    if (!flag1[r]) return;
    int c8 = (tid & 7) << 3;          // f32 col base
    int s = row_ptr[r];
    int e = row_ptr[r + 1];
    float dr = dinv[r];
    float acc[8] = {0.f, 0.f, 0.f, 0.f, 0.f, 0.f, 0.f, 0.f};
    for (int i = s; i < e; ++i) {
        int c = pcol[i];
        float v = dr * dinv[c];
        int sz = sizes[c];
        const float* p = ((c < N_USERS) ? ue + (size_t)c * D
                                        : ie + (size_t)(c - N_USERS) * D) + c8;
        float4 e0 = *(const float4*)p;
        float4 e1 = *(const float4*)(p + 4);
        acc[0] += v * ((c8 + 0 < sz) ? e0.x : 0.f);
        acc[1] += v * ((c8 + 1 < sz) ? e0.y : 0.f);
        acc[2] += v * ((c8 + 2 < sz) ? e0.z : 0.f);
        acc[3] += v * ((c8 + 3 < sz) ? e0.w : 0.f);
        acc[4] += v * ((c8 + 4 < sz) ? e1.x : 0.f);
        acc[5] += v * ((c8 + 5 < sz) ? e1.y : 0.f);
        acc[6] += v * ((c8 + 6 < sz) ? e1.z : 0.f);
        acc[7] += v * ((c8 + 7 < sz) ? e1.w : 0.f);
    }
    uint4 o;
    o.x = f2bf(acc[0]) | (f2bf(acc[1]) << 16);
    o.y = f2bf(acc[2]) | (f2bf(acc[3]) << 16);
    o.z = f2bf(acc[4]) | (f2bf(acc[5]) << 16);
    o.w = f2bf(acc[6]) | (f2bf(acc[7]) << 16);
    *(uint4*)(y1 + (size_t)r * 32 + (tid & 7) * 4) = o;
}

// ---------------------------------------------------------------------------
// Layer-2 bf16 SPMM, flag2 rows only: x2[r] = sum val * y1[col].
// ---------------------------------------------------------------------------
__global__ void k_spmm2(const int* __restrict__ row_ptr, const int* __restrict__ pcol,
                        const float* __restrict__ dinv, const char* __restrict__ flag2,
                        const unsigned* __restrict__ y1, unsigned* __restrict__ x2) {
    int tid = blockIdx.x * blockDim.x + threadIdx.x;
    int r = tid >> 3;
    if (r >= NNODES) return;
    if (!flag2[r]) return;
    int cp = (tid & 7) << 2;
    int s = row_ptr[r];
    int e = row_ptr[r + 1];
    float dr = dinv[r];
    float acc[8] = {0.f, 0.f, 0.f, 0.f, 0.f, 0.f, 0.f, 0.f};
    int i = s;
    for (; i + 1 < e; i += 2) {
        int c0 = pcol[i], c1 = pcol[i + 1];
        float v0 = dr * dinv[c0], v1 = dr * dinv[c1];
        uint4 w0 = *(const uint4*)(y1 + (size_t)c0 * 32 + cp);
        uint4 w1 = *(const uint4*)(y1 + (size_t)c1 * 32 + cp);
        unpack_fma(acc, w0, v0);
        unpack_fma(acc, w1, v1);
    }
    if (i < e) {
        int c0 = pcol[i];
        float v0 = dr * dinv[c0];
        uint4 w0 = *(const uint4*)(y1 + (size_t)c0 * 32 + cp);
        unpack_fma(acc, w0, v0);
    }
    uint4 o;
    o.x = f2bf(acc[0]) | (f2bf(acc[1]) << 16);
    o.y = f2bf(acc[2]) | (f2bf(acc[3]) << 16);
    o.z = f2bf(acc[4]) | (f2bf(acc[5]) << 16);
    o.w = f2bf(acc[6]) | (f2bf(acc[7]) << 16);
    *(uint4*)(x2 + (size_t)r * 32 + cp) = o;
}

// ---------------------------------------------------------------------------
// Final sampled layer, everything fused:
//   x0r   = masked f32 emb row (exact)
//   out[slot]      = (x0r + y1[r] + x2[r] + sum val * x2[col]) * 0.25
//   out[3B + slot] = x0r                     (ego)
// ---------------------------------------------------------------------------
__global__ void k_spmm3(const int* __restrict__ row_ptr, const int* __restrict__ pcol,
                        const float* __restrict__ dinv, const int* __restrict__ sizes,
                        const float* __restrict__ ue, const float* __restrict__ ie,
                        const unsigned* __restrict__ y1, const unsigned* __restrict__ x2,
                        const int* __restrict__ users, const int* __restrict__ pos,
                        const int* __restrict__ neg, float* __restrict__ out) {
    int tid = blockIdx.x * blockDim.x + threadIdx.x;
    int slot = tid >> 3;
    if (slot >= 3 * B) return;
    int cp = (tid & 7) << 2;          // uint base
    int c8 = (tid & 7) << 3;          // f32 col base
    int set = slot / B;
    int b = slot - set * B;
    int r;
    if (set == 0)      r = users[b];
    else if (set == 1) r = N_USERS + pos[b];
    else               r = N_USERS + neg[b];
    int s = row_ptr[r];
    int e = row_ptr[r + 1];
    float dr = dinv[r];
    float acc[8] = {0.f, 0.f, 0.f, 0.f, 0.f, 0.f, 0.f, 0.f};
    uint4 g1 = *(const uint4*)(y1 + (size_t)r * 32 + cp);
    uint4 g2 = *(const uint4*)(x2 + (size_t)r * 32 + cp);
    unpack_fma(acc, g1, 1.0f);
    unpack_fma(acc, g2, 1.0f);
    int i = s;
    for (; i + 1 < e; i += 2) {
        int c0 = pcol[i], c1 = pcol[i + 1];
        float v0 = dr * dinv[c0], v1 = dr * dinv[c1];
        uint4 w0 = *(const uint4*)(x2 + (size_t)c0 * 32 + cp);
        uint4 w1 = *(const uint4*)(x2 + (size_t)c1 * 32 + cp);
        unpack_fma(acc, w0, v0);
        unpack_fma(acc, w1, v1);
    }
    if (i < e) {
        int c0 = pcol[i];
        float v0 = dr * dinv[c0];
        uint4 w0 = *(const uint4*)(x2 + (size_t)c0 * 32 + cp);
        unpack_fma(acc, w0, v0);
    }
    // exact masked f32 ego row
    const float* p = ((r < N_USERS) ? ue + (size_t)r * D
                                    : ie + (size_t)(r - N_USERS) * D) + c8;
    float4 e0 = *(const float4*)p;
    float4 e1 = *(const float4*)(p + 4);
    int sz = sizes[r];
    e0.x = (c8 + 0 < sz) ? e0.x : 0.f; e0.y = (c8 + 1 < sz) ? e0.y : 0.f;
    e0.z = (c8 + 2 < sz) ? e0.z : 0.f; e0.w = (c8 + 3 < sz) ? e0.w : 0.f;
    e1.x = (c8 + 4 < sz) ? e1.x : 0.f; e1.y = (c8 + 5 < sz) ? e1.y : 0.f;
    e1.z = (c8 + 6 < sz) ? e1.z : 0.f; e1.w = (c8 + 7 < sz) ? e1.w : 0.f;
    float4 oa, ob;
    oa.x = (e0.x + acc[0]) * 0.25f; oa.y = (e0.y + acc[1]) * 0.25f;
    oa.z = (e0.z + acc[2]) * 0.25f; oa.w = (e0.w + acc[3]) * 0.25f;
    ob.x = (e1.x + acc[4]) * 0.25f; ob.y = (e1.y + acc[5]) * 0.25f;
    ob.z = (e1.z + acc[6]) * 0.25f; ob.w = (e1.w + acc[7]) * 0.25f;
    float* o0 = out + (size_t)slot * D + c8;
    float* o1 = out + (size_t)(3 * B + slot) * D + c8;
    *(float4*)o0 = oa; *(float4*)(o0 + 4) = ob;
    *(float4*)o1 = e0; *(float4*)(o1 + 4) = e1;
}

extern "C" void kernel_launch(void* const* d_in, const int* in_sizes, int n_in,
                              void* d_out, int out_size, void* d_ws, size_t ws_size,
                              hipStream_t stream) {
    const float* ue   = (const float*)d_in[0];
    const float* ie   = (const float*)d_in[1];
    const int*   um   = (const int*)d_in[2];
    const int*   im   = (const int*)d_in[3];
    const int*   rows = (const int*)d_in[4];
    const int*   cols = (const int*)d_in[5];
    const int*   users = (const int*)d_in[7];
    const int*   pos   = (const int*)d_in[8];
    const int*   neg   = (const int*)d_in[9];
    int nnz = in_sizes[4];

    float* out = (float*)d_out;

    // workspace layout (16B-aligned bf16 node buffers first)
    unsigned short* Y1 = (unsigned short*)d_ws;         // NNODES*D bf16
    unsigned short* X2 = Y1 + (size_t)NNODES * D;       // NNODES*D bf16
    int*   deg     = (int*)(X2 + (size_t)NNODES * D);   // NNODES
    int*   row_ptr = deg + NNODES;                      // NNODES+1
    int*   nextp   = row_ptr + NNODES + 1;              // NNODES
    int*   sizes   = nextp + NNODES;                    // NNODES
    int*   sums    = sizes + NNODES;                    // up to 4096
    float* dinv    = (float*)(sums + 4096);             // NNODES
    int*   pcol    = (int*)(dinv + NNODES);             // nnz
    char*  flag1   = (char*)(pcol + nnz);               // NNODES
    char*  flag2   = flag1 + NNODES;                    // NNODES

    const int blk = 256;
    const int scan_blocks = (NNODES + 255) / 256;       // 2344
    const int flag_blocks = (3 * B + blk - 1) / blk;    // 96

    // --- CSR build + flag clear ---
    hipMemsetAsync(deg, 0, (size_t)NNODES * sizeof(int), stream);
    hipMemsetAsync(flag1, 0, (size_t)2 * NNODES, stream);
    k_hist<<<(nnz + blk - 1) / blk, blk, 0, stream>>>(rows, deg, nnz);
    k_scan1<<<scan_blocks, 256, 0, stream>>>(deg, sums, dinv, NNODES);
    k_scan2<<<1, 1024, 0, stream>>>(sums, scan_blocks);
    k_scan3_flags<<<scan_blocks + flag_blocks, blk, 0, stream>>>(
        deg, sums, row_ptr, nextp, users, pos, neg, flag1, flag2, nnz, scan_blocks);

    // --- fat kernel: scatter || sizes || mark-pass1, role = bid % 10 ---
    {
        int groups = (nnz + 255) / 256;                 // 4688 (covers scatter & pass1)
        // sizes needs NNODES*16/256 = 37500 sub-blocks; groups*8 = 37504 >= ok
        k_fat<<<groups * 10, blk, 0, stream>>>(rows, cols, nextp, pcol,
                                               um, im, sizes, flag2, nnz);
    }

    // --- mark pass2: flag1 = flag2 U nbrs(flag2) ---
    k_pass2<<<(nnz + NNODES + blk - 1) / blk, blk, 0, stream>>>(rows, cols, flag2, flag1, nnz);

    int n_full = NNODES * 8;
    int n_samp = 3 * B * 8;

    // layer 1 (flag1 rows): Y1 = A * masked_emb
    k_spmm1<<<(n_full + blk - 1) / blk, blk, 0, stream>>>(row_ptr, pcol, dinv, sizes, flag1,
                                                          ue, ie, (unsigned*)Y1);

    // layer 2 (flag2 rows): X2 = A * Y1
    k_spmm2<<<(n_full + blk - 1) / blk, blk, 0, stream>>>(row_ptr, pcol, dinv, flag2,
                                                          (const unsigned*)Y1, (unsigned*)X2);

    // layer 3: sampled rows, fully fused epilogue + ego
    k_spmm3<<<(n_samp + blk - 1) / blk, blk, 0, stream>>>(row_ptr, pcol, dinv, sizes,
                                                          ue, ie,
                                                          (const unsigned*)Y1,
                                                          (const unsigned*)X2,
                                                          users, pos, neg, out);
}